// Round 5
// baseline (357.809 us; speedup 1.0000x reference)
//
#include <hip/hip_runtime.h>
#include <hip/hip_bf16.h>

#define IN_CH 128
#define HID_CH 64
#define OUT_CH 32
#define EPB 2048  // edges per partition block
#define MAXB 512  // max buckets (N <= 131072)

typedef unsigned short ushort_t;
typedef __attribute__((ext_vector_type(8))) short short8;
typedef __attribute__((ext_vector_type(4))) float float4v;
typedef __attribute__((ext_vector_type(4))) float fx4;
typedef __attribute__((ext_vector_type(4))) unsigned ux4;
using half8 = __attribute__((ext_vector_type(8))) _Float16;

static __device__ __forceinline__ ushort_t f2bf(float f) {
    unsigned u = __float_as_uint(f);
    unsigned r = (u + 0x7fff + ((u >> 16) & 1)) >> 16;  // RNE
    return (ushort_t)r;
}
static __device__ __forceinline__ float bf_lo(unsigned u) { return __uint_as_float(u << 16); }
static __device__ __forceinline__ float bf_hi(unsigned u) { return __uint_as_float(u & 0xffff0000u); }

static __device__ __forceinline__ unsigned f2h2(float lo, float hi) {  // RNE f32->f16 pair, packed
    union { _Float16 h[2]; unsigned u; } v;
    v.h[0] = (_Float16)lo;
    v.h[1] = (_Float16)hi;
    return v.u;
}
static __device__ __forceinline__ unsigned pkh(float a, float b) {  // RTZ packed cvt (fast path)
    auto p = __builtin_amdgcn_cvt_pkrtz(a, b);
    union { decltype(p) h; unsigned u; } v;
    v.h = p;
    return v.u;
}

// ---------------- radix partition by dst>>8 (+ prepW in 5 trailing blocks) ----------------

__global__ __launch_bounds__(256) void k_partition(const int* __restrict__ src,
                                                   const int* __restrict__ dst,
                                                   int* __restrict__ gcursor,
                                                   unsigned* __restrict__ pairs,
                                                   int E, int nbk, int cap, int PB,
                                                   const float* __restrict__ W1,
                                                   const float* __restrict__ W2,
                                                   unsigned* __restrict__ wsW) {
    __shared__ int lhist[MAXB];
    __shared__ int lbase[MAXB];
    __shared__ int lcur[MAXB];
    const int tid = threadIdx.x;

    if (blockIdx.x >= PB) {  // prepW blocks
        int s = (blockIdx.x - PB) * 256 + tid;  // 0..1279
        if (s < 1024) {                          // W1 -> bf16 b-frags
            int lane = s & 63;
            int nt = (s >> 6) & 3;
            int kc = s >> 8;
            int c = nt * 16 + (lane & 15);
            int k0 = kc * 32 + (lane >> 4) * 8;
            unsigned o[4];
#pragma unroll
            for (int d = 0; d < 4; ++d) {
                unsigned lo = f2bf(W1[(k0 + 2 * d) * 64 + c]);
                unsigned hi = f2bf(W1[(k0 + 2 * d + 1) * 64 + c]);
                o[d] = lo | (hi << 16);
            }
            ((uint4*)wsW)[s] = make_uint4(o[0], o[1], o[2], o[3]);
        } else {  // W2 -> f16 b-frags: frag f = kt*2+ct
            int q = s - 1024;  // 0..255
            int lane = q & 63;
            int f = q >> 6;
            int c = (f & 1) * 16 + (lane & 15);
            int k0 = (f >> 1) * 32 + (lane >> 4) * 8;
            unsigned o[4];
#pragma unroll
            for (int d = 0; d < 4; ++d)
                o[d] = f2h2(W2[(k0 + 2 * d) * 32 + c], W2[(k0 + 2 * d + 1) * 32 + c]);
            ((uint4*)wsW)[1024 + q] = make_uint4(o[0], o[1], o[2], o[3]);
        }
        return;
    }

    for (int b = tid; b < nbk; b += 256) { lhist[b] = 0; lcur[b] = 0; }
    __syncthreads();
    int s[8], d[8];
    const int e0 = blockIdx.x * EPB;
#pragma unroll
    for (int j = 0; j < 8; ++j) {
        int e = e0 + j * 256 + tid;
        if (e < E) {
            s[j] = src[e];
            d[j] = dst[e];
            atomicAdd(&lhist[d[j] >> 8], 1);
        } else {
            d[j] = -1;
        }
    }
    __syncthreads();
    for (int b = tid; b < nbk; b += 256)
        lbase[b] = lhist[b] ? atomicAdd(&gcursor[b], lhist[b]) : 0;
    __syncthreads();
#pragma unroll
    for (int j = 0; j < 8; ++j) {
        if (d[j] >= 0) {
            int b = d[j] >> 8;
            int loc = atomicAdd(&lcur[b], 1);
            int idx = lbase[b] + loc;
            if (idx < cap)
                pairs[(long long)b * cap + idx] = ((unsigned)s[j] << 8) | (unsigned)(d[j] & 255);
        }
    }
}

// ---------------- fused per-bucket build (inline bucket-total scan) ----------------
// Also zeroes the h1 PLANAR pad rows (8 planes x 16B) used by gather pad lanes.

__global__ __launch_bounds__(256) void k_bucket_build(const unsigned* __restrict__ pairs,
                                                      const int* __restrict__ gcursor,
                                                      int* __restrict__ rowptr,
                                                      int* __restrict__ col,
                                                      float* __restrict__ dis,
                                                      unsigned* __restrict__ h1d,
                                                      int cap, int N) {
    __shared__ int lc[256];
    __shared__ int ls[256];
    __shared__ int lcur[256];
    const int b = blockIdx.x, tid = threadIdx.x;

    if (b == 0 && tid < 32)  // plane p pad row: 16B = 4 dwords
        h1d[((long long)(tid >> 2) * (N + 1) + N) * 4 + (tid & 3)] = 0;

    int ga = min(gcursor[2 * tid], cap);
    int gb = min(gcursor[2 * tid + 1], cap);
    ls[tid] = ga + gb;
    __syncthreads();
    for (int off = 1; off < 256; off <<= 1) {
        int val = (tid >= off) ? ls[tid - off] : 0;
        __syncthreads();
        ls[tid] += val;
        __syncthreads();
    }
    const int p = b >> 1;
    const int base = (p ? ls[p - 1] : 0) + ((b & 1) ? min(gcursor[b - 1], cap) : 0);
    const int total = ls[255];
    __syncthreads();
    if (b == 0 && tid == 0) rowptr[N] = total;

    lc[tid] = 0;
    __syncthreads();
    const int cnt = min(gcursor[b], cap);
    const unsigned* pp = pairs + (long long)b * cap;
    for (int i = tid; i < cnt; i += 256) atomicAdd(&lc[pp[i] & 255], 1);
    __syncthreads();
    const int v = lc[tid];
    ls[tid] = v;
    __syncthreads();
    for (int off = 1; off < 256; off <<= 1) {
        int val = (tid >= off) ? ls[tid - off] : 0;
        __syncthreads();
        ls[tid] += val;
        __syncthreads();
    }
    const int excl = ls[tid] - v;
    const int row = b * 256 + tid;
    if (row < N) {
        rowptr[row] = base + excl;
        dis[row] = rsqrtf((float)(v + 1));  // +1 self-loop
    }
    lcur[tid] = base + excl;
    __syncthreads();
    for (int i = tid; i < cnt; i += 256) {
        unsigned pk = pp[i];
        int pos = atomicAdd(&lcur[pk & 255], 1);
        col[pos] = (int)(pk >> 8);
    }
}

// ---------------- L1 matmul via MFMA; PLANAR-8 output: plane p holds channels 8p..8p+7 ----------------
// h1'[p][row][8ch bf16 = 16B], pre-scaled by dis[row].

__global__ __launch_bounds__(256) void k_mm1(const float* __restrict__ X,
                                             const unsigned* __restrict__ wsW,
                                             const float* __restrict__ dis,
                                             ushort_t* __restrict__ H, int N) {
    const int tid = threadIdx.x;
    const int wv = tid >> 6, lane = tid & 63;
    const int quad = lane >> 4, n16 = lane & 15;
    const int rowbase = blockIdx.x * 64 + wv * 16;
    const int myrow = rowbase + n16;
    const bool rok = (myrow < N);

    float4v acc0 = {}, acc1 = {}, acc2 = {}, acc3 = {};

#pragma unroll
    for (int kc = 0; kc < 4; ++kc) {
        float4 xa = make_float4(0.f, 0.f, 0.f, 0.f), xb = xa;
        if (rok) {
            const float4* p = (const float4*)(X + (long long)myrow * 128 + kc * 32 + quad * 8);
            xa = p[0];
            xb = p[1];
        }
        unsigned pk[4];
        pk[0] = (unsigned)f2bf(xa.x) | ((unsigned)f2bf(xa.y) << 16);
        pk[1] = (unsigned)f2bf(xa.z) | ((unsigned)f2bf(xa.w) << 16);
        pk[2] = (unsigned)f2bf(xb.x) | ((unsigned)f2bf(xb.y) << 16);
        pk[3] = (unsigned)f2bf(xb.z) | ((unsigned)f2bf(xb.w) << 16);
        short8 a;
        a[0] = (short)(pk[0] & 0xffff); a[1] = (short)(pk[0] >> 16);
        a[2] = (short)(pk[1] & 0xffff); a[3] = (short)(pk[1] >> 16);
        a[4] = (short)(pk[2] & 0xffff); a[5] = (short)(pk[2] >> 16);
        a[6] = (short)(pk[3] & 0xffff); a[7] = (short)(pk[3] >> 16);

        const short8* wb = (const short8*)wsW;
        short8 b0 = wb[(kc * 4 + 0) * 64 + lane];
        short8 b1 = wb[(kc * 4 + 1) * 64 + lane];
        short8 b2 = wb[(kc * 4 + 2) * 64 + lane];
        short8 b3 = wb[(kc * 4 + 3) * 64 + lane];

        acc0 = __builtin_amdgcn_mfma_f32_16x16x32_bf16(a, b0, acc0, 0, 0, 0);
        acc1 = __builtin_amdgcn_mfma_f32_16x16x32_bf16(a, b1, acc1, 0, 0, 0);
        acc2 = __builtin_amdgcn_mfma_f32_16x16x32_bf16(a, b2, acc2, 0, 0, 0);
        acc3 = __builtin_amdgcn_mfma_f32_16x16x32_bf16(a, b3, acc3, 0, 0, 0);
    }

    const int pb = n16 >> 3, dd = n16 & 7;  // channel j*16+n16 -> plane j*2+pb, slot dd
#pragma unroll
    for (int i = 0; i < 4; ++i) {
        int row = rowbase + quad * 4 + i;
        if (row < N) {
            float dr = dis[row];
            H[((long long)(0 + pb) * (N + 1) + row) * 8 + dd] = f2bf(dr * acc0[i]);
            H[((long long)(2 + pb) * (N + 1) + row) * 8 + dd] = f2bf(dr * acc1[i]);
            H[((long long)(4 + pb) * (N + 1) + row) * 8 + dd] = f2bf(dr * acc2[i]);
            H[((long long)(6 + pb) * (N + 1) + row) * 8 + dd] = f2bf(dr * acc3[i]);
        }
    }
}

// ---------------- gather1: layer-1 aggregation, channel-eighth per XCD ----------------
// Block's XCD (bid&7) selects plane x (channels 8x..8x+7, 1.6MB -> fits 4MB private L2).
// One lane per row (64 rows/wave, 256/block); 24 unconditional slots + 8-wide overflow tier.
// z[x][row] = relu(b1 + dr*(sum nbrs + self)) packed f16, nontemporal store.

__global__ __launch_bounds__(256, 8) void k_gather1(const unsigned* __restrict__ h,
                                                    const int* __restrict__ rowptr,
                                                    const int* __restrict__ col,
                                                    const float* __restrict__ dis,
                                                    const float* __restrict__ b1,
                                                    unsigned* __restrict__ z,
                                                    int N, int nunits) {
    const int tid = threadIdx.x;
    const int wv = tid >> 6, lane = tid & 63;
    const int x = blockIdx.x & 7;   // XCD -> channel-eighth
    const int j = blockIdx.x >> 3;
    const int jn = gridDim.x >> 3;

    const uint4* h8 = (const uint4*)h + (long long)x * (N + 1);
    unsigned* z8 = z + (long long)x * (N + 1) * 4;
    const float4 ba = ((const float4*)b1)[x * 2];
    const float4 bb = ((const float4*)b1)[x * 2 + 1];

    for (int r = j; r < nunits; r += jn) {
        const int row = r * 256 + wv * 64 + lane;
        const int rme = min(row, N);
        const int sg = rowptr[rme];
        const int dg = rowptr[min(rme + 1, N)] - sg;
        const float drg = (row < N) ? dis[row] : 0.f;

        int mc[24];
#pragma unroll
        for (int u = 0; u < 24; ++u)
            mc[u] = (u < dg) ? __builtin_nontemporal_load(col + sg + u) : N;

        uint4 us = h8[rme];  // self-loop (pre-scaled)
        float2 p0 = make_float2(bf_lo(us.x), bf_hi(us.x));
        float2 p1 = make_float2(bf_lo(us.y), bf_hi(us.y));
        float2 p2 = make_float2(bf_lo(us.z), bf_hi(us.z));
        float2 p3 = make_float2(bf_lo(us.w), bf_hi(us.w));

#pragma unroll
        for (int u = 0; u < 24; ++u) {
            uint4 uu = h8[mc[u]];
            p0 += make_float2(bf_lo(uu.x), bf_hi(uu.x));
            p1 += make_float2(bf_lo(uu.y), bf_hi(uu.y));
            p2 += make_float2(bf_lo(uu.z), bf_hi(uu.z));
            p3 += make_float2(bf_lo(uu.w), bf_hi(uu.w));
        }
        for (int base = 24; __any(base < dg); base += 8) {  // rare overflow tier
            int m2[8];
#pragma unroll
            for (int u = 0; u < 8; ++u)
                m2[u] = (base + u < dg) ? __builtin_nontemporal_load(col + sg + base + u) : N;
#pragma unroll
            for (int u = 0; u < 8; ++u) {
                uint4 uu = h8[m2[u]];
                p0 += make_float2(bf_lo(uu.x), bf_hi(uu.x));
                p1 += make_float2(bf_lo(uu.y), bf_hi(uu.y));
                p2 += make_float2(bf_lo(uu.z), bf_hi(uu.z));
                p3 += make_float2(bf_lo(uu.w), bf_hi(uu.w));
            }
        }

        if (row < N) {
            float z0 = fmaxf(fmaf(drg, p0.x, ba.x), 0.f);
            float z1 = fmaxf(fmaf(drg, p0.y, ba.y), 0.f);
            float z2 = fmaxf(fmaf(drg, p1.x, ba.z), 0.f);
            float z3 = fmaxf(fmaf(drg, p1.y, ba.w), 0.f);
            float z4 = fmaxf(fmaf(drg, p2.x, bb.x), 0.f);
            float z5 = fmaxf(fmaf(drg, p2.y, bb.y), 0.f);
            float z6 = fmaxf(fmaf(drg, p3.x, bb.z), 0.f);
            float z7 = fmaxf(fmaf(drg, p3.y, bb.w), 0.f);
            ux4 zo;
            zo.x = pkh(z0, z1);
            zo.y = pkh(z2, z3);
            zo.z = pkh(z4, z5);
            zo.w = pkh(z6, z7);
            __builtin_nontemporal_store(zo, (ux4*)(z8 + (long long)row * 4));
        }
    }
}

// ---------------- mm2: h2' = dis[row] * (z @ W2), z from 8 f16 planes, h2 PLANAR-2 bf16 ----------------
// Also zeroes the h2 pad rows (2 planes x 32B).

__global__ __launch_bounds__(256) void k_mm2(const unsigned* __restrict__ z,
                                             const unsigned* __restrict__ wsW2,
                                             const float* __restrict__ dis,
                                             ushort_t* __restrict__ H2, int N) {
    const int tid = threadIdx.x;
    if (blockIdx.x == 0 && tid < 16)
        ((unsigned*)H2)[((long long)(tid >> 3) * (N + 1) + N) * 8 + (tid & 7)] = 0;

    const int wv = tid >> 6, lane = tid & 63;
    const int n16 = lane & 15, kq = lane >> 4;
    const int rowbase = blockIdx.x * 64 + wv * 16;
    const int rz = min(rowbase + n16, N - 1);

    const uint4* z4 = (const uint4*)z;
    uint4 a0 = z4[(long long)kq * (N + 1) + rz];        // k = kq*8..+8   (channels = k)
    uint4 a1 = z4[(long long)(4 + kq) * (N + 1) + rz];  // k = 32+kq*8..+8

    const half8* wfh = (const half8*)wsW2;
    const half8 bf00 = wfh[lane];
    const half8 bf01 = wfh[64 + lane];
    const half8 bf10 = wfh[128 + lane];
    const half8 bf11 = wfh[192 + lane];

    union U { uint4 u; half8 h; };
    U ua0, ua1;
    ua0.u = a0;
    ua1.u = a1;

    float4v c0 = {}, c1 = {};
    c0 = __builtin_amdgcn_mfma_f32_16x16x32_f16(ua0.h, bf00, c0, 0, 0, 0);
    c0 = __builtin_amdgcn_mfma_f32_16x16x32_f16(ua1.h, bf10, c0, 0, 0, 0);
    c1 = __builtin_amdgcn_mfma_f32_16x16x32_f16(ua0.h, bf01, c1, 0, 0, 0);
    c1 = __builtin_amdgcn_mfma_f32_16x16x32_f16(ua1.h, bf11, c1, 0, 0, 0);

    float dis_l = (lane < 16 && rowbase + lane < N) ? dis[rowbase + lane] : 0.f;
#pragma unroll
    for (int i = 0; i < 4; ++i) {
        int rr = rowbase + kq * 4 + i;  // C row = (lane>>4)*4 + reg
        float dr = __shfl(dis_l, kq * 4 + i);
        if (rr < N) {
            H2[(long long)rr * 16 + n16] = f2bf(dr * c0[i]);                    // plane 0: ch n16
            H2[((long long)(N + 1) + rr) * 16 + n16] = f2bf(dr * c1[i]);        // plane 1: ch 16+n16
        }
    }
}

// ---------------- agg32: final aggregation, channel-half per XCD-quad ----------------
// h2 planar-2 (3.2MB/plane fits 4MB L2). One lane per row; 16 slots + 8-wide tier.
// out[row][hh*16..+16) fp32 = full 64B line per row, nontemporal.

__global__ __launch_bounds__(256, 8) void k_agg32(const unsigned* __restrict__ h2,
                                                  const int* __restrict__ rowptr,
                                                  const int* __restrict__ col,
                                                  const float* __restrict__ dis,
                                                  const float* __restrict__ b2,
                                                  float* __restrict__ out, int N, int nunits) {
    const int tid = threadIdx.x;
    const int wv = tid >> 6, lane = tid & 63;
    const int xcd = blockIdx.x & 7;
    const int hh = xcd >> 2, sub = xcd & 3;
    const int j = blockIdx.x >> 3;

    const uint4* hw = (const uint4*)h2 + (long long)hh * (N + 1) * 2;
    const float4 bq0 = ((const float4*)b2)[hh * 4 + 0];
    const float4 bq1 = ((const float4*)b2)[hh * 4 + 1];
    const float4 bq2 = ((const float4*)b2)[hh * 4 + 2];
    const float4 bq3 = ((const float4*)b2)[hh * 4 + 3];

    const int r = j * 4 + sub;
    if (r >= nunits) return;
    const int row = r * 256 + wv * 64 + lane;
    const int rme = min(row, N);
    const int sg = rowptr[rme];
    const int dg = rowptr[min(rme + 1, N)] - sg;
    const float drg = (row < N) ? dis[row] : 0.f;

    int mc[16];
#pragma unroll
    for (int u = 0; u < 16; ++u)
        mc[u] = (u < dg) ? __builtin_nontemporal_load(col + sg + u) : N;

    uint4 ua = hw[(long long)rme * 2];
    uint4 ub = hw[(long long)rme * 2 + 1];
    float2 p0 = make_float2(bf_lo(ua.x), bf_hi(ua.x));
    float2 p1 = make_float2(bf_lo(ua.y), bf_hi(ua.y));
    float2 p2 = make_float2(bf_lo(ua.z), bf_hi(ua.z));
    float2 p3 = make_float2(bf_lo(ua.w), bf_hi(ua.w));
    float2 p4 = make_float2(bf_lo(ub.x), bf_hi(ub.x));
    float2 p5 = make_float2(bf_lo(ub.y), bf_hi(ub.y));
    float2 p6 = make_float2(bf_lo(ub.z), bf_hi(ub.z));
    float2 p7 = make_float2(bf_lo(ub.w), bf_hi(ub.w));

#define ACC2(S)                                                        \
    {                                                                  \
        uint4 va = hw[(long long)(S) * 2];                             \
        uint4 vb = hw[(long long)(S) * 2 + 1];                         \
        p0 += make_float2(bf_lo(va.x), bf_hi(va.x));                   \
        p1 += make_float2(bf_lo(va.y), bf_hi(va.y));                   \
        p2 += make_float2(bf_lo(va.z), bf_hi(va.z));                   \
        p3 += make_float2(bf_lo(va.w), bf_hi(va.w));                   \
        p4 += make_float2(bf_lo(vb.x), bf_hi(vb.x));                   \
        p5 += make_float2(bf_lo(vb.y), bf_hi(vb.y));                   \
        p6 += make_float2(bf_lo(vb.z), bf_hi(vb.z));                   \
        p7 += make_float2(bf_lo(vb.w), bf_hi(vb.w));                   \
    }
#pragma unroll
    for (int u = 0; u < 16; ++u) ACC2(mc[u])
    for (int base = 16; __any(base < dg); base += 8) {
        int m2[8];
#pragma unroll
        for (int u = 0; u < 8; ++u)
            m2[u] = (base + u < dg) ? __builtin_nontemporal_load(col + sg + base + u) : N;
#pragma unroll
        for (int u = 0; u < 8; ++u) ACC2(m2[u])
    }
#undef ACC2

    if (row < N) {
        fx4 o0, o1, o2, o3;
        o0.x = bq0.x + drg * p0.x; o0.y = bq0.y + drg * p0.y;
        o0.z = bq0.z + drg * p1.x; o0.w = bq0.w + drg * p1.y;
        o1.x = bq1.x + drg * p2.x; o1.y = bq1.y + drg * p2.y;
        o1.z = bq1.z + drg * p3.x; o1.w = bq1.w + drg * p3.y;
        o2.x = bq2.x + drg * p4.x; o2.y = bq2.y + drg * p4.y;
        o2.z = bq2.z + drg * p5.x; o2.w = bq2.w + drg * p5.y;
        o3.x = bq3.x + drg * p6.x; o3.y = bq3.y + drg * p6.y;
        o3.z = bq3.z + drg * p7.x; o3.w = bq3.w + drg * p7.y;
        fx4* op = (fx4*)(out + (long long)row * 32 + hh * 16);
        __builtin_nontemporal_store(o0, op);
        __builtin_nontemporal_store(o1, op + 1);
        __builtin_nontemporal_store(o2, op + 2);
        __builtin_nontemporal_store(o3, op + 3);
    }
}

extern "C" void kernel_launch(void* const* d_in, const int* in_sizes, int n_in,
                              void* d_out, int out_size, void* d_ws, size_t ws_size,
                              hipStream_t stream) {
    const float* x  = (const float*)d_in[0];
    const int*   ei = (const int*)d_in[1];
    const float* W1 = (const float*)d_in[2];
    const float* b1 = (const float*)d_in[3];
    const float* W2 = (const float*)d_in[4];
    const float* b2 = (const float*)d_in[5];
    float* out = (float*)d_out;

    const int N = in_sizes[0] / IN_CH;
    const int E = in_sizes[1] / 2;
    const int* esrc = ei;
    const int* edst = ei + E;

    int nbk = (N + 255) >> 8;
    if (nbk > MAXB) nbk = MAXB;
    const int per_b = (E + nbk - 1) / nbk;
    const int cap = per_b + per_b / 4 + 256;  // ~20-sigma headroom

    // workspace layout (4-byte units, regions padded to 16)
    // h1: PLANAR-8 bf16, plane p = channels 8p..8p+7, (N+1) rows x 16B  (12.8MB)
    // z (scratch, after pairs dead): PLANAR-8 f16, (N+1) x 16B per plane (12.8MB)
    // h2: PLANAR-2 bf16 halves, (N+1) x 32B per plane -- aliases h1 region (h1 dead by mm2)
    int* rowptr   = (int*)d_ws;                          // N+1
    int* gcursor  = rowptr + (((N + 1) + 15) & ~15);     // MAXB
    unsigned* wsW = (unsigned*)(gcursor + MAXB);         // 4096 W1-frag + 1024 W2-frag dwords
    int* col      = (int*)(wsW + 5120);                  // E
    float* dis    = (float*)(col + ((E + 15) & ~15));    // N
    ushort_t* h1  = (ushort_t*)(dis + ((N + 15) & ~15)); // 8*(N+1)*8 bf16
    unsigned* scratch = (unsigned*)(h1 + (((long long)(N + 1) * 64 + 31) & ~31LL));
    unsigned* pairs = scratch;            // nbk*cap dwords (~8.4MB), dead after bucket_build
    unsigned* z     = scratch;            // 8*(N+1)*4 dwords f16 planes (12.8MB)
    ushort_t* h2    = h1;                 // 2*(N+1)*16 bf16 halves (6.4MB), after h1 dead

    const int B = 256;
    const int PB = (E + EPB - 1) / EPB;
    const int NU = (N + 255) >> 8;        // 256-row units (391)
    const int G1J = 196;                  // gather1: per-XCD blocks, 2 units each
    const int G2J = (NU + 3) / 4;         // agg32: per-XCD-quad sub-stride, 1 unit each

    hipMemsetAsync(gcursor, 0, MAXB * sizeof(int), stream);
    k_partition<<<PB + 5, B, 0, stream>>>(esrc, edst, gcursor, pairs, E, nbk, cap, PB, W1, W2, wsW);
    k_bucket_build<<<nbk, B, 0, stream>>>(pairs, gcursor, rowptr, col, dis, (unsigned*)h1, cap, N);

    k_mm1<<<(N + 63) / 64, B, 0, stream>>>(x, wsW, dis, h1, N);

    // layer-1 aggregation: 8 channel-planes, one per XCD, L2-resident gathers
    k_gather1<<<8 * G1J, B, 0, stream>>>((const unsigned*)h1, rowptr, col, dis, b1, z, N, NU);

    // layer-2 transform (MFMA), writes h2 over dead h1
    k_mm2<<<(N + 63) / 64, B, 0, stream>>>(z, wsW + 4096, dis, h2, N);

    // final aggregation: 2 channel-halves, one per XCD-quad
    k_agg32<<<8 * G2J, B, 0, stream>>>((const unsigned*)h2, rowptr, col, dis, b2, out, N, NU);
}

// Round 6
// 235.356 us; speedup vs baseline: 1.5203x; 1.5203x over previous
//
#include <hip/hip_runtime.h>
#include <hip/hip_bf16.h>

#define IN_CH 128
#define HID_CH 64
#define OUT_CH 32
#define EPB 2048  // edges per partition block
#define MAXB 512  // max buckets (N <= 131072)

typedef unsigned short ushort_t;
typedef __attribute__((ext_vector_type(8))) short short8;
typedef __attribute__((ext_vector_type(4))) float float4v;
using half8 = __attribute__((ext_vector_type(8))) _Float16;

static __device__ __forceinline__ ushort_t f2bf(float f) {
    unsigned u = __float_as_uint(f);
    unsigned r = (u + 0x7fff + ((u >> 16) & 1)) >> 16;  // RNE
    return (ushort_t)r;
}
static __device__ __forceinline__ float bf_lo(unsigned u) { return __uint_as_float(u << 16); }
static __device__ __forceinline__ float bf_hi(unsigned u) { return __uint_as_float(u & 0xffff0000u); }

static __device__ __forceinline__ unsigned f2h2(float lo, float hi) {  // RNE f32->f16 pair, packed
    union { _Float16 h[2]; unsigned u; } v;
    v.h[0] = (_Float16)lo;
    v.h[1] = (_Float16)hi;
    return v.u;
}
static __device__ __forceinline__ unsigned pkh(float a, float b) {  // RTZ packed cvt (fast path)
    auto p = __builtin_amdgcn_cvt_pkrtz(a, b);
    union { decltype(p) h; unsigned u; } v;
    v.h = p;
    return v.u;
}

// ---------------- radix partition by dst>>8 (+ prepW in 5 trailing blocks) ----------------

__global__ __launch_bounds__(256) void k_partition(const int* __restrict__ src,
                                                   const int* __restrict__ dst,
                                                   int* __restrict__ gcursor,
                                                   unsigned* __restrict__ pairs,
                                                   int E, int nbk, int cap, int PB,
                                                   const float* __restrict__ W1,
                                                   const float* __restrict__ W2,
                                                   unsigned* __restrict__ wsW) {
    __shared__ int lhist[MAXB];
    __shared__ int lbase[MAXB];
    __shared__ int lcur[MAXB];
    const int tid = threadIdx.x;

    if (blockIdx.x >= PB) {  // prepW blocks
        int s = (blockIdx.x - PB) * 256 + tid;  // 0..1279
        if (s < 1024) {                          // W1 -> bf16 b-frags
            int lane = s & 63;
            int nt = (s >> 6) & 3;
            int kc = s >> 8;
            int c = nt * 16 + (lane & 15);
            int k0 = kc * 32 + (lane >> 4) * 8;
            unsigned o[4];
#pragma unroll
            for (int d = 0; d < 4; ++d) {
                unsigned lo = f2bf(W1[(k0 + 2 * d) * 64 + c]);
                unsigned hi = f2bf(W1[(k0 + 2 * d + 1) * 64 + c]);
                o[d] = lo | (hi << 16);
            }
            ((uint4*)wsW)[s] = make_uint4(o[0], o[1], o[2], o[3]);
        } else {  // W2 -> f16 b-frags: frag f = kt*2+ct
            int q = s - 1024;  // 0..255
            int lane = q & 63;
            int f = q >> 6;
            int c = (f & 1) * 16 + (lane & 15);
            int k0 = (f >> 1) * 32 + (lane >> 4) * 8;
            unsigned o[4];
#pragma unroll
            for (int d = 0; d < 4; ++d)
                o[d] = f2h2(W2[(k0 + 2 * d) * 32 + c], W2[(k0 + 2 * d + 1) * 32 + c]);
            ((uint4*)wsW)[1024 + q] = make_uint4(o[0], o[1], o[2], o[3]);
        }
        return;
    }

    for (int b = tid; b < nbk; b += 256) { lhist[b] = 0; lcur[b] = 0; }
    __syncthreads();
    int s[8], d[8];
    const int e0 = blockIdx.x * EPB;
#pragma unroll
    for (int j = 0; j < 8; ++j) {
        int e = e0 + j * 256 + tid;
        if (e < E) {
            s[j] = src[e];
            d[j] = dst[e];
            atomicAdd(&lhist[d[j] >> 8], 1);
        } else {
            d[j] = -1;
        }
    }
    __syncthreads();
    for (int b = tid; b < nbk; b += 256)
        lbase[b] = lhist[b] ? atomicAdd(&gcursor[b], lhist[b]) : 0;
    __syncthreads();
#pragma unroll
    for (int j = 0; j < 8; ++j) {
        if (d[j] >= 0) {
            int b = d[j] >> 8;
            int loc = atomicAdd(&lcur[b], 1);
            int idx = lbase[b] + loc;
            if (idx < cap)
                pairs[(long long)b * cap + idx] = ((unsigned)s[j] << 8) | (unsigned)(d[j] & 255);
        }
    }
}

// ---------------- fused per-bucket build (inline bucket-total scan) ----------------

__global__ __launch_bounds__(256) void k_bucket_build(const unsigned* __restrict__ pairs,
                                                      const int* __restrict__ gcursor,
                                                      int* __restrict__ rowptr,
                                                      int* __restrict__ col,
                                                      float* __restrict__ dis,
                                                      unsigned* __restrict__ h1zero,
                                                      int cap, int N) {
    __shared__ int lc[256];
    __shared__ int ls[256];
    __shared__ int lcur[256];
    const int b = blockIdx.x, tid = threadIdx.x;

    if (b == 0 && tid < 32) h1zero[tid] = 0;  // h1 pad row (64 bf16 = 32 dwords)

    int ga = min(gcursor[2 * tid], cap);
    int gb = min(gcursor[2 * tid + 1], cap);
    ls[tid] = ga + gb;
    __syncthreads();
    for (int off = 1; off < 256; off <<= 1) {
        int val = (tid >= off) ? ls[tid - off] : 0;
        __syncthreads();
        ls[tid] += val;
        __syncthreads();
    }
    const int p = b >> 1;
    const int base = (p ? ls[p - 1] : 0) + ((b & 1) ? min(gcursor[b - 1], cap) : 0);
    const int total = ls[255];
    __syncthreads();
    if (b == 0 && tid == 0) rowptr[N] = total;

    lc[tid] = 0;
    __syncthreads();
    const int cnt = min(gcursor[b], cap);
    const unsigned* pp = pairs + (long long)b * cap;
    for (int i = tid; i < cnt; i += 256) atomicAdd(&lc[pp[i] & 255], 1);
    __syncthreads();
    const int v = lc[tid];
    ls[tid] = v;
    __syncthreads();
    for (int off = 1; off < 256; off <<= 1) {
        int val = (tid >= off) ? ls[tid - off] : 0;
        __syncthreads();
        ls[tid] += val;
        __syncthreads();
    }
    const int excl = ls[tid] - v;
    const int row = b * 256 + tid;
    if (row < N) {
        rowptr[row] = base + excl;
        dis[row] = rsqrtf((float)(v + 1));  // +1 self-loop
    }
    lcur[tid] = base + excl;
    __syncthreads();
    for (int i = tid; i < cnt; i += 256) {
        unsigned pk = pp[i];
        int pos = atomicAdd(&lcur[pk & 255], 1);
        col[pos] = (int)(pk >> 8);
    }
}

// ---------------- L1 matmul via MFMA; output pre-scaled: h1' = dis[row]*(x@W1) ----------------

__global__ __launch_bounds__(256) void k_mm1(const float* __restrict__ X,
                                             const unsigned* __restrict__ wsW,
                                             const float* __restrict__ dis,
                                             ushort_t* __restrict__ H,
                                             unsigned* __restrict__ h2zero, int N) {
    const int tid = threadIdx.x;
    if (blockIdx.x == 0 && tid < 16) h2zero[tid] = 0;  // h2 pad row (32 bf16 = 16 dwords)

    const int wv = tid >> 6, lane = tid & 63;
    const int quad = lane >> 4, n16 = lane & 15;
    const int rowbase = blockIdx.x * 64 + wv * 16;
    const int myrow = rowbase + n16;
    const bool rok = (myrow < N);

    float4v acc0 = {}, acc1 = {}, acc2 = {}, acc3 = {};

#pragma unroll
    for (int kc = 0; kc < 4; ++kc) {
        float4 xa = make_float4(0.f, 0.f, 0.f, 0.f), xb = xa;
        if (rok) {
            const float4* p = (const float4*)(X + (long long)myrow * 128 + kc * 32 + quad * 8);
            xa = p[0];
            xb = p[1];
        }
        unsigned pk[4];
        pk[0] = (unsigned)f2bf(xa.x) | ((unsigned)f2bf(xa.y) << 16);
        pk[1] = (unsigned)f2bf(xa.z) | ((unsigned)f2bf(xa.w) << 16);
        pk[2] = (unsigned)f2bf(xb.x) | ((unsigned)f2bf(xb.y) << 16);
        pk[3] = (unsigned)f2bf(xb.z) | ((unsigned)f2bf(xb.w) << 16);
        short8 a;
        a[0] = (short)(pk[0] & 0xffff); a[1] = (short)(pk[0] >> 16);
        a[2] = (short)(pk[1] & 0xffff); a[3] = (short)(pk[1] >> 16);
        a[4] = (short)(pk[2] & 0xffff); a[5] = (short)(pk[2] >> 16);
        a[6] = (short)(pk[3] & 0xffff); a[7] = (short)(pk[3] >> 16);

        const short8* wb = (const short8*)wsW;
        short8 b0 = wb[(kc * 4 + 0) * 64 + lane];
        short8 b1 = wb[(kc * 4 + 1) * 64 + lane];
        short8 b2 = wb[(kc * 4 + 2) * 64 + lane];
        short8 b3 = wb[(kc * 4 + 3) * 64 + lane];

        acc0 = __builtin_amdgcn_mfma_f32_16x16x32_bf16(a, b0, acc0, 0, 0, 0);
        acc1 = __builtin_amdgcn_mfma_f32_16x16x32_bf16(a, b1, acc1, 0, 0, 0);
        acc2 = __builtin_amdgcn_mfma_f32_16x16x32_bf16(a, b2, acc2, 0, 0, 0);
        acc3 = __builtin_amdgcn_mfma_f32_16x16x32_bf16(a, b3, acc3, 0, 0, 0);
    }

#pragma unroll
    for (int i = 0; i < 4; ++i) {
        int row = rowbase + quad * 4 + i;
        if (row < N) {
            float dr = dis[row];
            long long o = (long long)row * 64 + n16;
            H[o]      = f2bf(dr * acc0[i]);
            H[o + 16] = f2bf(dr * acc1[i]);
            H[o + 32] = f2bf(dr * acc2[i]);
            H[o + 48] = f2bf(dr * acc3[i]);
        }
    }
}

// ---------------- fused agg64 + mm2 v4: 8 rows/wave, 8-lane row-groups, no reduce ----------------
// Static strided persistent loop, BALANCED grid (exactly 2 iterations/wave).
// Epilogue: LDS transpose (obuf) -> one coalesced 512B uint2 store per 8-row group
// (replaces 32x 2B scattered stores/row: round-3 WRITE_SIZE 16.5MB vs 6.4MB logical).

__global__ __launch_bounds__(256, 8) void k_agg64_mm2(const unsigned* __restrict__ h,
                                                      const int* __restrict__ rowptr,
                                                      const int* __restrict__ col,
                                                      const float* __restrict__ dis,
                                                      const float* __restrict__ b1,
                                                      const unsigned* __restrict__ wsW2,
                                                      unsigned* __restrict__ h2, int N) {
    __shared__ __align__(16) _Float16 zbl[4][8][72];   // pad 72: 144B row stride
    __shared__ __align__(16) ushort_t obuf[4][8][40];  // 80B row stride, <=2-way aliasing
    const int tid = threadIdx.x;
    const int wv = tid >> 6, lane = tid & 63;
    const int t = lane & 7, g = lane >> 3;
    const float4 bqa = ((const float4*)b1)[2 * t];      // channels 8t..8t+3
    const float4 bqb = ((const float4*)b1)[2 * t + 1];  // channels 8t+4..8t+7

    const half8* wfh = (const half8*)wsW2;  // W2 f16 b-frags
    const half8 bf00 = wfh[lane];
    const half8 bf01 = wfh[64 + lane];
    const half8 bf10 = wfh[128 + lane];
    const half8 bf11 = wfh[192 + lane];

    uint2* H2w = (uint2*)h2;  // h2 row = 64B = 8 uint2
    const uint4* h4 = (const uint4*)h;
    const int NB = (N + 7) >> 3;
    const int step = gridDim.x * 4;

    for (int rb = blockIdx.x * 4 + wv; rb < NB; rb += step) {
        const int r0 = rb * 8;
        int rp_l = rowptr[min(r0 + min(lane, 8), N)];
        float dis_l = (lane < 8 && r0 + lane < N) ? dis[r0 + lane] : 0.f;
        const int sg = __shfl(rp_l, g);
        const int dg = __shfl(rp_l, g + 1) - sg;
        const float drg = __shfl(dis_l, g);
        float dr03[4];  // dis of rows (lane>>4&1)*4 + i, for the C-store
#pragma unroll
        for (int i = 0; i < 4; ++i) dr03[i] = __shfl(dis_l, ((lane >> 4) & 1) * 4 + i);

        int mc1 = N, mc2 = N, mc3 = N;
        if (t < dg)      mc1 = col[sg + t];
        if (8 + t < dg)  mc2 = col[sg + 8 + t];
        if (16 + t < dg) mc3 = col[sg + 16 + t];

        const int rme = min(r0 + g, N);
        uint4 us = h4[rme * 8 + t];  // self-loop slice
        float2 p0 = make_float2(bf_lo(us.x), bf_hi(us.x));
        float2 p1 = make_float2(bf_lo(us.y), bf_hi(us.y));
        float2 p2 = make_float2(bf_lo(us.z), bf_hi(us.z));
        float2 p3 = make_float2(bf_lo(us.w), bf_hi(us.w));

#define GATX(MC, U)                                                   \
    {                                                                 \
        int s_ = __shfl((MC), (g << 3) + (U));                        \
        uint4 uu = h4[s_ * 8 + t];                                    \
        p0 += make_float2(bf_lo(uu.x), bf_hi(uu.x));                  \
        p1 += make_float2(bf_lo(uu.y), bf_hi(uu.y));                  \
        p2 += make_float2(bf_lo(uu.z), bf_hi(uu.z));                  \
        p3 += make_float2(bf_lo(uu.w), bf_hi(uu.w));                  \
    }
#pragma unroll
        for (int u = 0; u < 8; ++u) GATX(mc1, u)
#pragma unroll
        for (int u = 0; u < 8; ++u) GATX(mc2, u)
#pragma unroll
        for (int u = 0; u < 8; ++u) GATX(mc3, u)
        if (__any(dg > 24)) {
            int mc4 = N;
            if (24 + t < dg) mc4 = col[sg + 24 + t];
#pragma unroll
            for (int u = 0; u < 8; ++u) GATX(mc4, u)
        }
        for (int u = 32; u < dg; ++u) {  // ultra-rare serial tail (same-addr broadcast col)
            int s_ = col[sg + u];
            uint4 uu = h4[s_ * 8 + t];
            p0 += make_float2(bf_lo(uu.x), bf_hi(uu.x));
            p1 += make_float2(bf_lo(uu.y), bf_hi(uu.y));
            p2 += make_float2(bf_lo(uu.z), bf_hi(uu.z));
            p3 += make_float2(bf_lo(uu.w), bf_hi(uu.w));
        }
#undef GATX

        // z = relu(b1 + dr*acc) -> f16, lane writes its own 16B slice; no cross-lane reduce
        {
            float z0 = fmaxf(fmaf(drg, p0.x, bqa.x), 0.f);
            float z1 = fmaxf(fmaf(drg, p0.y, bqa.y), 0.f);
            float z2 = fmaxf(fmaf(drg, p1.x, bqa.z), 0.f);
            float z3 = fmaxf(fmaf(drg, p1.y, bqa.w), 0.f);
            float z4 = fmaxf(fmaf(drg, p2.x, bqb.x), 0.f);
            float z5 = fmaxf(fmaf(drg, p2.y, bqb.y), 0.f);
            float z6 = fmaxf(fmaf(drg, p3.x, bqb.z), 0.f);
            float z7 = fmaxf(fmaf(drg, p3.y, bqb.w), 0.f);
            *(uint4*)&zbl[wv][g][8 * t] =
                make_uint4(pkh(z0, z1), pkh(z2, z3), pkh(z4, z5), pkh(z6, z7));
        }
        __builtin_amdgcn_wave_barrier();

        // batched MFMA: A row = lane&15 (rows 8-15 replicate rows 0-7, C rows 8-15 unused)
        const int zr = lane & 7;
        const int ko = (lane >> 4) * 8;
        half8 af0 = *(const half8*)&zbl[wv][zr][ko];
        half8 af1 = *(const half8*)&zbl[wv][zr][ko + 32];
        float4v c0 = {}, c1 = {};
        c0 = __builtin_amdgcn_mfma_f32_16x16x32_f16(af0, bf00, c0, 0, 0, 0);
        c0 = __builtin_amdgcn_mfma_f32_16x16x32_f16(af1, bf10, c0, 0, 0, 0);
        c1 = __builtin_amdgcn_mfma_f32_16x16x32_f16(af0, bf01, c1, 0, 0, 0);
        c1 = __builtin_amdgcn_mfma_f32_16x16x32_f16(af1, bf11, c1, 0, 0, 0);
        __builtin_amdgcn_wave_barrier();

        // epilogue: C rows 0-7 in lanes 0-31 (row = (lane>>4)*4 + reg, col = lane&15)
        // -> LDS transpose -> one coalesced 512B store for the 8-row group
        if (lane < 32) {
            const int li = lane >> 4;
            const int cc = lane & 15;
#pragma unroll
            for (int i = 0; i < 4; ++i) {
                const int lr = li * 4 + i;
                obuf[wv][lr][cc]      = f2bf(dr03[i] * c0[i]);
                obuf[wv][lr][16 + cc] = f2bf(dr03[i] * c1[i]);
            }
        }
        __builtin_amdgcn_wave_barrier();
        {
            const int lr = lane >> 3;   // 0..7 local row
            const int qq = lane & 7;    // 8B chunk
            const int rr = r0 + lr;
            if (rr < N) {
                uint2 val = *(const uint2*)&obuf[wv][lr][qq * 4];
                H2w[(long long)rr * 8 + qq] = val;
            }
        }
        __builtin_amdgcn_wave_barrier();
    }
}

// ---------------- agg32 v4: 8 rows/wave, 8-lane row-groups, no reduce, balanced grid ----------------

__global__ __launch_bounds__(256, 8) void k_agg32(const unsigned* __restrict__ h,
                                                  const int* __restrict__ rowptr,
                                                  const int* __restrict__ col,
                                                  const float* __restrict__ dis,
                                                  const float* __restrict__ b,
                                                  float* __restrict__ out, int N) {
    const int tid = threadIdx.x;
    const int wv = tid >> 6, lane = tid & 63;
    const int t = lane & 7, g = lane >> 3;
    const float4 bq = ((const float4*)b)[t];  // channels 4t..4t+3
    const uint2* hw = (const uint2*)h;
    const int NB = (N + 7) >> 3;
    const int step = gridDim.x * 4;

    for (int rb = blockIdx.x * 4 + wv; rb < NB; rb += step) {
        const int r0 = rb * 8;
        int rp_l = rowptr[min(r0 + min(lane, 8), N)];
        float dis_l = (lane < 8 && r0 + lane < N) ? dis[r0 + lane] : 0.f;
        const int sg = __shfl(rp_l, g);
        const int dg = __shfl(rp_l, g + 1) - sg;
        const float drg = __shfl(dis_l, g);

        int mc1 = N, mc2 = N, mc3 = N;
        if (t < dg)      mc1 = col[sg + t];
        if (8 + t < dg)  mc2 = col[sg + 8 + t];
        if (16 + t < dg) mc3 = col[sg + 16 + t];

        const int rme = min(r0 + g, N);
        uint2 us = hw[rme * 8 + t];  // self-loop slice
        float2 p0 = make_float2(bf_lo(us.x), bf_hi(us.x));
        float2 p1 = make_float2(bf_lo(us.y), bf_hi(us.y));

#define GAT2(MC, U)                                                   \
    {                                                                 \
        int s_ = __shfl((MC), (g << 3) + (U));                        \
        uint2 uu = hw[s_ * 8 + t];                                    \
        p0 += make_float2(bf_lo(uu.x), bf_hi(uu.x));                  \
        p1 += make_float2(bf_lo(uu.y), bf_hi(uu.y));                  \
    }
#pragma unroll
        for (int u = 0; u < 8; ++u) GAT2(mc1, u)
#pragma unroll
        for (int u = 0; u < 8; ++u) GAT2(mc2, u)
#pragma unroll
        for (int u = 0; u < 8; ++u) GAT2(mc3, u)
        if (__any(dg > 24)) {
            int mc4 = N;
            if (24 + t < dg) mc4 = col[sg + 24 + t];
#pragma unroll
            for (int u = 0; u < 8; ++u) GAT2(mc4, u)
        }
        for (int u = 32; u < dg; ++u) {
            int s_ = col[sg + u];
            uint2 uu = hw[s_ * 8 + t];
            p0 += make_float2(bf_lo(uu.x), bf_hi(uu.x));
            p1 += make_float2(bf_lo(uu.y), bf_hi(uu.y));
        }
#undef GAT2

        const int rr = r0 + g;
        if (rr < N) {
            float4 o;
            o.x = bq.x + drg * p0.x;
            o.y = bq.y + drg * p0.y;
            o.z = bq.z + drg * p1.x;
            o.w = bq.w + drg * p1.y;
            ((float4*)out)[(long long)rr * 8 + t] = o;
        }
    }
}

extern "C" void kernel_launch(void* const* d_in, const int* in_sizes, int n_in,
                              void* d_out, int out_size, void* d_ws, size_t ws_size,
                              hipStream_t stream) {
    const float* x  = (const float*)d_in[0];
    const int*   ei = (const int*)d_in[1];
    const float* W1 = (const float*)d_in[2];
    const float* b1 = (const float*)d_in[3];
    const float* W2 = (const float*)d_in[4];
    const float* b2 = (const float*)d_in[5];
    float* out = (float*)d_out;

    const int N = in_sizes[0] / IN_CH;
    const int E = in_sizes[1] / 2;
    const int* esrc = ei;
    const int* edst = ei + E;

    int nbk = (N + 255) >> 8;
    if (nbk > MAXB) nbk = MAXB;
    const int per_b = (E + nbk - 1) / nbk;
    const int cap = per_b + per_b / 4 + 256;  // ~20-sigma headroom

    // workspace layout (4-byte units, regions padded to 16); h1/h2 have pad row N
    int* rowptr   = (int*)d_ws;                          // N+1
    int* gcursor  = rowptr + (((N + 1) + 15) & ~15);     // MAXB
    unsigned* wsW = (unsigned*)(gcursor + MAXB);         // 4096 W1-frag + 1024 W2-frag dwords
    int* col      = (int*)(wsW + 5120);                  // E
    float* dis    = (float*)(col + ((E + 15) & ~15));    // N
    ushort_t* h1  = (ushort_t*)(dis + ((N + 15) & ~15)); // (N+1)*64 bf16
    unsigned* scratch = (unsigned*)(h1 + (((long long)(N + 1) * 64 + 31) & ~31LL));
    unsigned* pairs = scratch;        // nbk*cap dwords (~8.4MB), dead after bucket_build
    unsigned* h2    = scratch;        // (N+1)*16 dwords bf16x2, written after pairs dead

    const int B = 256;
    const int PB = (E + EPB - 1) / EPB;
    const int NB = (N + 7) >> 3;
    // Balanced persistent grid: exactly 2 row-blocks per wave (waves*2 >= NB),
    // all blocks co-resident (<= 2048 at 8 blocks/CU). Round-3 ran 2048 blocks at
    // 76% slot utilization (1.52 iters/wave imbalance); this is ~100%.
    int agg_blocks = (NB + 7) / 8;            // = ceil(NB / (4 waves * 2 iters))
    if (agg_blocks > 2048) agg_blocks = 2048; // safety for larger N

    hipMemsetAsync(gcursor, 0, MAXB * sizeof(int), stream);
    k_partition<<<PB + 5, B, 0, stream>>>(esrc, edst, gcursor, pairs, E, nbk, cap, PB, W1, W2, wsW);
    k_bucket_build<<<nbk, B, 0, stream>>>(pairs, gcursor, rowptr, col, dis,
                                          (unsigned*)(h1 + (long long)N * 64), cap, N);

    k_mm1<<<(N + 63) / 64, B, 0, stream>>>(x, wsW, dis, h1, h2 + (long long)N * 16, N);

    k_agg64_mm2<<<agg_blocks, B, 0, stream>>>((const unsigned*)h1, rowptr, col, dis, b1,
                                              wsW + 4096, h2, N);

    k_agg32<<<agg_blocks, B, 0, stream>>>((const unsigned*)h2, rowptr, col, dis, b2, out, N);
}

// Round 7
// 232.675 us; speedup vs baseline: 1.5378x; 1.0115x over previous
//
#include <hip/hip_runtime.h>
#include <hip/hip_bf16.h>

#define IN_CH 128
#define HID_CH 64
#define OUT_CH 32
#define EPB 2048  // edges per partition block
#define MAXB 512  // max buckets (N <= 131072)

typedef unsigned short ushort_t;
typedef __attribute__((ext_vector_type(8))) short short8;
typedef __attribute__((ext_vector_type(4))) float float4v;
typedef __attribute__((ext_vector_type(4))) float fx4;
typedef __attribute__((ext_vector_type(4))) unsigned ux4;
using half8 = __attribute__((ext_vector_type(8))) _Float16;

static __device__ __forceinline__ ushort_t f2bf(float f) {
    unsigned u = __float_as_uint(f);
    unsigned r = (u + 0x7fff + ((u >> 16) & 1)) >> 16;  // RNE
    return (ushort_t)r;
}
static __device__ __forceinline__ float bf_lo(unsigned u) { return __uint_as_float(u << 16); }
static __device__ __forceinline__ float bf_hi(unsigned u) { return __uint_as_float(u & 0xffff0000u); }

static __device__ __forceinline__ unsigned f2h2(float lo, float hi) {  // RNE f32->f16 pair, packed
    union { _Float16 h[2]; unsigned u; } v;
    v.h[0] = (_Float16)lo;
    v.h[1] = (_Float16)hi;
    return v.u;
}
static __device__ __forceinline__ unsigned pkh(float a, float b) {  // RTZ packed cvt (fast path)
    auto p = __builtin_amdgcn_cvt_pkrtz(a, b);
    union { decltype(p) h; unsigned u; } v;
    v.h = p;
    return v.u;
}

// ---------------- radix partition by dst>>8 (+ prepW in 5 trailing blocks) ----------------

__global__ __launch_bounds__(256) void k_partition(const int* __restrict__ src,
                                                   const int* __restrict__ dst,
                                                   int* __restrict__ gcursor,
                                                   unsigned* __restrict__ pairs,
                                                   int E, int nbk, int cap, int PB,
                                                   const float* __restrict__ W1,
                                                   const float* __restrict__ W2,
                                                   unsigned* __restrict__ wsW) {
    __shared__ int lhist[MAXB];
    __shared__ int lbase[MAXB];
    __shared__ int lcur[MAXB];
    const int tid = threadIdx.x;

    if (blockIdx.x >= PB) {  // prepW blocks
        int s = (blockIdx.x - PB) * 256 + tid;  // 0..1279
        if (s < 1024) {                          // W1 -> bf16 b-frags
            int lane = s & 63;
            int nt = (s >> 6) & 3;
            int kc = s >> 8;
            int c = nt * 16 + (lane & 15);
            int k0 = kc * 32 + (lane >> 4) * 8;
            unsigned o[4];
#pragma unroll
            for (int d = 0; d < 4; ++d) {
                unsigned lo = f2bf(W1[(k0 + 2 * d) * 64 + c]);
                unsigned hi = f2bf(W1[(k0 + 2 * d + 1) * 64 + c]);
                o[d] = lo | (hi << 16);
            }
            ((uint4*)wsW)[s] = make_uint4(o[0], o[1], o[2], o[3]);
        } else {  // W2 -> f16 b-frags: frag f = kt*2+ct
            int q = s - 1024;  // 0..255
            int lane = q & 63;
            int f = q >> 6;
            int c = (f & 1) * 16 + (lane & 15);
            int k0 = (f >> 1) * 32 + (lane >> 4) * 8;
            unsigned o[4];
#pragma unroll
            for (int d = 0; d < 4; ++d)
                o[d] = f2h2(W2[(k0 + 2 * d) * 32 + c], W2[(k0 + 2 * d + 1) * 32 + c]);
            ((uint4*)wsW)[1024 + q] = make_uint4(o[0], o[1], o[2], o[3]);
        }
        return;
    }

    for (int b = tid; b < nbk; b += 256) { lhist[b] = 0; lcur[b] = 0; }
    __syncthreads();
    int s[8], d[8];
    const int e0 = blockIdx.x * EPB;
#pragma unroll
    for (int j = 0; j < 8; ++j) {
        int e = e0 + j * 256 + tid;
        if (e < E) {
            s[j] = src[e];
            d[j] = dst[e];
            atomicAdd(&lhist[d[j] >> 8], 1);
        } else {
            d[j] = -1;
        }
    }
    __syncthreads();
    for (int b = tid; b < nbk; b += 256)
        lbase[b] = lhist[b] ? atomicAdd(&gcursor[b], lhist[b]) : 0;
    __syncthreads();
#pragma unroll
    for (int j = 0; j < 8; ++j) {
        if (d[j] >= 0) {
            int b = d[j] >> 8;
            int loc = atomicAdd(&lcur[b], 1);
            int idx = lbase[b] + loc;
            if (idx < cap)
                pairs[(long long)b * cap + idx] = ((unsigned)s[j] << 8) | (unsigned)(d[j] & 255);
        }
    }
}

// ---------------- fused per-bucket build (inline bucket-total scan) ----------------
// Also zeroes the h1 HALF pad rows (2 halves x 64B) used by gather pad lanes.

__global__ __launch_bounds__(256) void k_bucket_build(const unsigned* __restrict__ pairs,
                                                      const int* __restrict__ gcursor,
                                                      int* __restrict__ rowptr,
                                                      int* __restrict__ col,
                                                      float* __restrict__ dis,
                                                      unsigned* __restrict__ h1d,
                                                      int cap, int N) {
    __shared__ int lc[256];
    __shared__ int ls[256];
    __shared__ int lcur[256];
    const int b = blockIdx.x, tid = threadIdx.x;

    if (b == 0 && tid < 32)  // half hf pad row: 32 bf16 = 16 dwords
        h1d[(long long)(tid >> 4) * (N + 1) * 16 + (long long)N * 16 + (tid & 15)] = 0;

    int ga = min(gcursor[2 * tid], cap);
    int gb = min(gcursor[2 * tid + 1], cap);
    ls[tid] = ga + gb;
    __syncthreads();
    for (int off = 1; off < 256; off <<= 1) {
        int val = (tid >= off) ? ls[tid - off] : 0;
        __syncthreads();
        ls[tid] += val;
        __syncthreads();
    }
    const int p = b >> 1;
    const int base = (p ? ls[p - 1] : 0) + ((b & 1) ? min(gcursor[b - 1], cap) : 0);
    const int total = ls[255];
    __syncthreads();
    if (b == 0 && tid == 0) rowptr[N] = total;

    lc[tid] = 0;
    __syncthreads();
    const int cnt = min(gcursor[b], cap);
    const unsigned* pp = pairs + (long long)b * cap;
    for (int i = tid; i < cnt; i += 256) atomicAdd(&lc[pp[i] & 255], 1);
    __syncthreads();
    const int v = lc[tid];
    ls[tid] = v;
    __syncthreads();
    for (int off = 1; off < 256; off <<= 1) {
        int val = (tid >= off) ? ls[tid - off] : 0;
        __syncthreads();
        ls[tid] += val;
        __syncthreads();
    }
    const int excl = ls[tid] - v;
    const int row = b * 256 + tid;
    if (row < N) {
        rowptr[row] = base + excl;
        dis[row] = rsqrtf((float)(v + 1));  // +1 self-loop
    }
    lcur[tid] = base + excl;
    __syncthreads();
    for (int i = tid; i < cnt; i += 256) {
        unsigned pk = pp[i];
        int pos = atomicAdd(&lcur[pk & 255], 1);
        col[pos] = (int)(pk >> 8);
    }
}

// ---------------- L1 matmul via MFMA; HALF-2 output: half hf = channels 32hf..32hf+31 ----------------
// h1'[hf][row][32ch bf16 = 64B = one cache line], pre-scaled by dis[row].

__global__ __launch_bounds__(256) void k_mm1(const float* __restrict__ X,
                                             const unsigned* __restrict__ wsW,
                                             const float* __restrict__ dis,
                                             ushort_t* __restrict__ H, int N) {
    const int tid = threadIdx.x;
    const int wv = tid >> 6, lane = tid & 63;
    const int quad = lane >> 4, n16 = lane & 15;
    const int rowbase = blockIdx.x * 64 + wv * 16;
    const int myrow = rowbase + n16;
    const bool rok = (myrow < N);

    float4v acc0 = {}, acc1 = {}, acc2 = {}, acc3 = {};

#pragma unroll
    for (int kc = 0; kc < 4; ++kc) {
        float4 xa = make_float4(0.f, 0.f, 0.f, 0.f), xb = xa;
        if (rok) {
            const float4* p = (const float4*)(X + (long long)myrow * 128 + kc * 32 + quad * 8);
            xa = p[0];
            xb = p[1];
        }
        unsigned pk[4];
        pk[0] = (unsigned)f2bf(xa.x) | ((unsigned)f2bf(xa.y) << 16);
        pk[1] = (unsigned)f2bf(xa.z) | ((unsigned)f2bf(xa.w) << 16);
        pk[2] = (unsigned)f2bf(xb.x) | ((unsigned)f2bf(xb.y) << 16);
        pk[3] = (unsigned)f2bf(xb.z) | ((unsigned)f2bf(xb.w) << 16);
        short8 a;
        a[0] = (short)(pk[0] & 0xffff); a[1] = (short)(pk[0] >> 16);
        a[2] = (short)(pk[1] & 0xffff); a[3] = (short)(pk[1] >> 16);
        a[4] = (short)(pk[2] & 0xffff); a[5] = (short)(pk[2] >> 16);
        a[6] = (short)(pk[3] & 0xffff); a[7] = (short)(pk[3] >> 16);

        const short8* wb = (const short8*)wsW;
        short8 b0 = wb[(kc * 4 + 0) * 64 + lane];
        short8 b1 = wb[(kc * 4 + 1) * 64 + lane];
        short8 b2 = wb[(kc * 4 + 2) * 64 + lane];
        short8 b3 = wb[(kc * 4 + 3) * 64 + lane];

        acc0 = __builtin_amdgcn_mfma_f32_16x16x32_bf16(a, b0, acc0, 0, 0, 0);
        acc1 = __builtin_amdgcn_mfma_f32_16x16x32_bf16(a, b1, acc1, 0, 0, 0);
        acc2 = __builtin_amdgcn_mfma_f32_16x16x32_bf16(a, b2, acc2, 0, 0, 0);
        acc3 = __builtin_amdgcn_mfma_f32_16x16x32_bf16(a, b3, acc3, 0, 0, 0);
    }

    const long long hb1 = (long long)(N + 1) * 32;  // half-1 base (ushort units)
#pragma unroll
    for (int i = 0; i < 4; ++i) {
        int row = rowbase + quad * 4 + i;
        if (row < N) {
            float dr = dis[row];
            long long o = (long long)row * 32 + n16;
            H[o]            = f2bf(dr * acc0[i]);  // ch n16       (half 0)
            H[o + 16]       = f2bf(dr * acc1[i]);  // ch 16+n16    (half 0)
            H[hb1 + o]      = f2bf(dr * acc2[i]);  // ch 32+n16    (half 1)
            H[hb1 + o + 16] = f2bf(dr * acc3[i]);  // ch 48+n16    (half 1)
        }
    }
}

// ---------------- gather1h: layer-1 aggregation, channel-HALF per XCD-quad ----------------
// hf = (blockIdx&7)>>2: XCDs 0-3 gather half 0, XCDs 4-7 half 1. Working set 6.4MB vs 4MB L2
// (hit ~62% vs 31% unsplit). Rows are one 64B line; 4-lane groups x 16B; 16 rows/wave.
// z[hf][row][32ch f16] = relu(b1 + dr*(sum nbrs + self)), nontemporal store.

__global__ __launch_bounds__(256, 8) void k_gather1h(const unsigned* __restrict__ h,
                                                     const int* __restrict__ rowptr,
                                                     const int* __restrict__ col,
                                                     const float* __restrict__ dis,
                                                     const float* __restrict__ b1,
                                                     unsigned* __restrict__ z, int N) {
    const int tid = threadIdx.x;
    const int wv = tid >> 6, lane = tid & 63;
    const int t = lane & 3, g = lane >> 2;  // 16 groups x 4 lanes
    const int xcd = blockIdx.x & 7;
    const int hf = xcd >> 2;
    const int pb = ((blockIdx.x >> 3) << 2) | (xcd & 3);  // per-half block id
    const int nwh = ((gridDim.x >> 3) << 2) * 4;          // waves per half

    const uint4* h4 = (const uint4*)h + (long long)hf * (N + 1) * 4;  // 64B rows
    ux4* zp = (ux4*)z + (long long)hf * (N + 1) * 4;
    const float4 ba = ((const float4*)b1)[hf * 8 + t * 2];      // ch 32hf+8t..+3
    const float4 bb = ((const float4*)b1)[hf * 8 + t * 2 + 1];  // ch 32hf+8t+4..+7

    const int NBR = (N + 15) >> 4;

    for (int ri = pb * 4 + wv; ri < NBR; ri += nwh) {
        const int r0 = ri * 16;
        int rp_l = rowptr[min(r0 + min(lane, 16), N)];
        float dis_l = (lane < 16 && r0 + lane < N) ? dis[r0 + lane] : 0.f;
        const int sg = __shfl(rp_l, g);
        const int dg = __shfl(rp_l, g + 1) - sg;
        const float drg = __shfl(dis_l, g);
        const int rme = min(r0 + g, N);

        int mc0 = N, mc1 = N, mc2 = N, mc3 = N, mc4 = N, mc5 = N;
        if (t < dg)      mc0 = __builtin_nontemporal_load(col + sg + t);
        if (4 + t < dg)  mc1 = __builtin_nontemporal_load(col + sg + 4 + t);
        if (8 + t < dg)  mc2 = __builtin_nontemporal_load(col + sg + 8 + t);
        if (12 + t < dg) mc3 = __builtin_nontemporal_load(col + sg + 12 + t);
        if (16 + t < dg) mc4 = __builtin_nontemporal_load(col + sg + 16 + t);
        if (20 + t < dg) mc5 = __builtin_nontemporal_load(col + sg + 20 + t);

        uint4 us = h4[(long long)rme * 4 + t];  // self-loop slice (pre-scaled)
        float2 p0 = make_float2(bf_lo(us.x), bf_hi(us.x));
        float2 p1 = make_float2(bf_lo(us.y), bf_hi(us.y));
        float2 p2 = make_float2(bf_lo(us.z), bf_hi(us.z));
        float2 p3 = make_float2(bf_lo(us.w), bf_hi(us.w));

#define GATH(MC, J)                                                   \
    {                                                                 \
        int s_ = __shfl((MC), (g << 2) + (J));                        \
        uint4 uu = h4[(long long)s_ * 4 + t];                         \
        p0 += make_float2(bf_lo(uu.x), bf_hi(uu.x));                  \
        p1 += make_float2(bf_lo(uu.y), bf_hi(uu.y));                  \
        p2 += make_float2(bf_lo(uu.z), bf_hi(uu.z));                  \
        p3 += make_float2(bf_lo(uu.w), bf_hi(uu.w));                  \
    }
#pragma unroll
        for (int j = 0; j < 4; ++j) GATH(mc0, j)
#pragma unroll
        for (int j = 0; j < 4; ++j) GATH(mc1, j)
#pragma unroll
        for (int j = 0; j < 4; ++j) GATH(mc2, j)
#pragma unroll
        for (int j = 0; j < 4; ++j) GATH(mc3, j)
#pragma unroll
        for (int j = 0; j < 4; ++j) GATH(mc4, j)
#pragma unroll
        for (int j = 0; j < 4; ++j) GATH(mc5, j)
        if (__any(dg > 24)) {
            int mc6 = N, mc7 = N;
            if (24 + t < dg) mc6 = __builtin_nontemporal_load(col + sg + 24 + t);
            if (28 + t < dg) mc7 = __builtin_nontemporal_load(col + sg + 28 + t);
#pragma unroll
            for (int j = 0; j < 4; ++j) GATH(mc6, j)
#pragma unroll
            for (int j = 0; j < 4; ++j) GATH(mc7, j)
        }
        for (int u = 32;; ++u) {  // ultra-rare serial tail (broadcast col within group)
            bool act = u < dg;
            if (!__any(act)) break;
            if (act) {
                int s_ = col[sg + u];
                uint4 uu = h4[(long long)s_ * 4 + t];
                p0 += make_float2(bf_lo(uu.x), bf_hi(uu.x));
                p1 += make_float2(bf_lo(uu.y), bf_hi(uu.y));
                p2 += make_float2(bf_lo(uu.z), bf_hi(uu.z));
                p3 += make_float2(bf_lo(uu.w), bf_hi(uu.w));
            }
        }
#undef GATH

        if (r0 + g < N) {
            float z0 = fmaxf(fmaf(drg, p0.x, ba.x), 0.f);
            float z1 = fmaxf(fmaf(drg, p0.y, ba.y), 0.f);
            float z2 = fmaxf(fmaf(drg, p1.x, ba.z), 0.f);
            float z3 = fmaxf(fmaf(drg, p1.y, ba.w), 0.f);
            float z4 = fmaxf(fmaf(drg, p2.x, bb.x), 0.f);
            float z5 = fmaxf(fmaf(drg, p2.y, bb.y), 0.f);
            float z6 = fmaxf(fmaf(drg, p3.x, bb.z), 0.f);
            float z7 = fmaxf(fmaf(drg, p3.y, bb.w), 0.f);
            ux4 zo;
            zo.x = pkh(z0, z1);
            zo.y = pkh(z2, z3);
            zo.z = pkh(z4, z5);
            zo.w = pkh(z6, z7);
            __builtin_nontemporal_store(zo, zp + (long long)(r0 + g) * 4 + t);
        }
    }
}

// ---------------- mm2: h2' = dis[row]*(z @ W2); z from 2 f16 halves; h2 HALF-2 bf16 ----------------
// Verified fragment path (round-5 k_mm2, refchecked); only z/h2 base indexing changed.
// Also zeroes the h2 pad rows (2 halves x 32B).

__global__ __launch_bounds__(256) void k_mm2(const unsigned* __restrict__ z,
                                             const unsigned* __restrict__ wsW2,
                                             const float* __restrict__ dis,
                                             ushort_t* __restrict__ H2, int N) {
    const int tid = threadIdx.x;
    if (blockIdx.x == 0 && tid < 16)
        ((unsigned*)H2)[(long long)(tid >> 3) * (N + 1) * 8 + (long long)N * 8 + (tid & 7)] = 0;

    const int wv = tid >> 6, lane = tid & 63;
    const int n16 = lane & 15, kq = lane >> 4;
    const int rowbase = blockIdx.x * 64 + wv * 16;
    const int rz = min(rowbase + n16, N - 1);

    const uint4* z4 = (const uint4*)z;
    uint4 a0 = z4[(long long)rz * 4 + kq];                          // half0: ch 8kq..+7
    uint4 a1 = z4[(long long)(N + 1) * 4 + (long long)rz * 4 + kq]; // half1: ch 32+8kq..+7

    const half8* wfh = (const half8*)wsW2;
    const half8 bf00 = wfh[lane];
    const half8 bf01 = wfh[64 + lane];
    const half8 bf10 = wfh[128 + lane];
    const half8 bf11 = wfh[192 + lane];

    union U { uint4 u; half8 h; };
    U ua0, ua1;
    ua0.u = a0;
    ua1.u = a1;

    float4v c0 = {}, c1 = {};
    c0 = __builtin_amdgcn_mfma_f32_16x16x32_f16(ua0.h, bf00, c0, 0, 0, 0);
    c0 = __builtin_amdgcn_mfma_f32_16x16x32_f16(ua1.h, bf10, c0, 0, 0, 0);
    c1 = __builtin_amdgcn_mfma_f32_16x16x32_f16(ua0.h, bf01, c1, 0, 0, 0);
    c1 = __builtin_amdgcn_mfma_f32_16x16x32_f16(ua1.h, bf11, c1, 0, 0, 0);

    float dis_l = (lane < 16 && rowbase + lane < N) ? dis[rowbase + lane] : 0.f;
    const long long hb1 = (long long)(N + 1) * 16;
#pragma unroll
    for (int i = 0; i < 4; ++i) {
        int rr = rowbase + kq * 4 + i;  // C row = (lane>>4)*4 + reg
        float dr = __shfl(dis_l, kq * 4 + i);
        if (rr < N) {
            H2[(long long)rr * 16 + n16]       = f2bf(dr * c0[i]);  // half0: ch n16
            H2[hb1 + (long long)rr * 16 + n16] = f2bf(dr * c1[i]);  // half1: ch 16+n16
        }
    }
}

// ---------------- agg32h: final aggregation, channel-half per XCD-quad ----------------
// h2 halves 3.2MB -> fully L2-resident per XCD. 4-lane groups x 8B; 16 rows/wave.
// out[row][16hf..+16) fp32, nontemporal 16B/lane (64B/row-half contiguous).

__global__ __launch_bounds__(256, 8) void k_agg32h(const unsigned* __restrict__ h2,
                                                   const int* __restrict__ rowptr,
                                                   const int* __restrict__ col,
                                                   const float* __restrict__ dis,
                                                   const float* __restrict__ b2,
                                                   float* __restrict__ out, int N) {
    const int tid = threadIdx.x;
    const int wv = tid >> 6, lane = tid & 63;
    const int t = lane & 3, g = lane >> 2;
    const int xcd = blockIdx.x & 7;
    const int hf = xcd >> 2;
    const int pb = ((blockIdx.x >> 3) << 2) | (xcd & 3);
    const int nwh = ((gridDim.x >> 3) << 2) * 4;

    const uint2* hw = (const uint2*)h2 + (long long)hf * (N + 1) * 4;  // 32B rows
    const float4 bq = ((const float4*)b2)[hf * 4 + t];  // ch 16hf+4t..+3

    const int NBR = (N + 15) >> 4;

    for (int ri = pb * 4 + wv; ri < NBR; ri += nwh) {
        const int r0 = ri * 16;
        int rp_l = rowptr[min(r0 + min(lane, 16), N)];
        float dis_l = (lane < 16 && r0 + lane < N) ? dis[r0 + lane] : 0.f;
        const int sg = __shfl(rp_l, g);
        const int dg = __shfl(rp_l, g + 1) - sg;
        const float drg = __shfl(dis_l, g);
        const int rme = min(r0 + g, N);

        int mc0 = N, mc1 = N, mc2 = N, mc3 = N, mc4 = N, mc5 = N;
        if (t < dg)      mc0 = __builtin_nontemporal_load(col + sg + t);
        if (4 + t < dg)  mc1 = __builtin_nontemporal_load(col + sg + 4 + t);
        if (8 + t < dg)  mc2 = __builtin_nontemporal_load(col + sg + 8 + t);
        if (12 + t < dg) mc3 = __builtin_nontemporal_load(col + sg + 12 + t);
        if (16 + t < dg) mc4 = __builtin_nontemporal_load(col + sg + 16 + t);
        if (20 + t < dg) mc5 = __builtin_nontemporal_load(col + sg + 20 + t);

        uint2 us = hw[(long long)rme * 4 + t];  // self-loop slice
        float2 p0 = make_float2(bf_lo(us.x), bf_hi(us.x));
        float2 p1 = make_float2(bf_lo(us.y), bf_hi(us.y));

#define GATH2(MC, J)                                                  \
    {                                                                 \
        int s_ = __shfl((MC), (g << 2) + (J));                        \
        uint2 uu = hw[(long long)s_ * 4 + t];                         \
        p0 += make_float2(bf_lo(uu.x), bf_hi(uu.x));                  \
        p1 += make_float2(bf_lo(uu.y), bf_hi(uu.y));                  \
    }
#pragma unroll
        for (int j = 0; j < 4; ++j) GATH2(mc0, j)
#pragma unroll
        for (int j = 0; j < 4; ++j) GATH2(mc1, j)
#pragma unroll
        for (int j = 0; j < 4; ++j) GATH2(mc2, j)
#pragma unroll
        for (int j = 0; j < 4; ++j) GATH2(mc3, j)
#pragma unroll
        for (int j = 0; j < 4; ++j) GATH2(mc4, j)
#pragma unroll
        for (int j = 0; j < 4; ++j) GATH2(mc5, j)
        if (__any(dg > 24)) {
            int mc6 = N, mc7 = N;
            if (24 + t < dg) mc6 = __builtin_nontemporal_load(col + sg + 24 + t);
            if (28 + t < dg) mc7 = __builtin_nontemporal_load(col + sg + 28 + t);
#pragma unroll
            for (int j = 0; j < 4; ++j) GATH2(mc6, j)
#pragma unroll
            for (int j = 0; j < 4; ++j) GATH2(mc7, j)
        }
        for (int u = 32;; ++u) {
            bool act = u < dg;
            if (!__any(act)) break;
            if (act) {
                int s_ = col[sg + u];
                uint2 uu = hw[(long long)s_ * 4 + t];
                p0 += make_float2(bf_lo(uu.x), bf_hi(uu.x));
                p1 += make_float2(bf_lo(uu.y), bf_hi(uu.y));
            }
        }
#undef GATH2

        if (r0 + g < N) {
            fx4 o;
            o.x = bq.x + drg * p0.x;
            o.y = bq.y + drg * p0.y;
            o.z = bq.z + drg * p1.x;
            o.w = bq.w + drg * p1.y;
            fx4* op = (fx4*)(out + (long long)(r0 + g) * 32 + hf * 16 + t * 4);
            __builtin_nontemporal_store(o, op);
        }
    }
}

extern "C" void kernel_launch(void* const* d_in, const int* in_sizes, int n_in,
                              void* d_out, int out_size, void* d_ws, size_t ws_size,
                              hipStream_t stream) {
    const float* x  = (const float*)d_in[0];
    const int*   ei = (const int*)d_in[1];
    const float* W1 = (const float*)d_in[2];
    const float* b1 = (const float*)d_in[3];
    const float* W2 = (const float*)d_in[4];
    const float* b2 = (const float*)d_in[5];
    float* out = (float*)d_out;

    const int N = in_sizes[0] / IN_CH;
    const int E = in_sizes[1] / 2;
    const int* esrc = ei;
    const int* edst = ei + E;

    int nbk = (N + 255) >> 8;
    if (nbk > MAXB) nbk = MAXB;
    const int per_b = (E + nbk - 1) / nbk;
    const int cap = per_b + per_b / 4 + 256;  // ~20-sigma headroom

    // workspace layout (4-byte units, regions padded to 16)
    // h1: HALF-2 bf16, half hf = ch 32hf..+31, (N+1) x 64B each (12.8MB total)
    // z (scratch, pairs dead): HALF-2 f16, (N+1) x 64B each (12.8MB)
    // h2: HALF-2 bf16, (N+1) x 32B each (6.4MB) -- aliases h1 region (h1 dead after gather1h)
    int* rowptr   = (int*)d_ws;                          // N+1
    int* gcursor  = rowptr + (((N + 1) + 15) & ~15);     // MAXB
    unsigned* wsW = (unsigned*)(gcursor + MAXB);         // 4096 W1-frag + 1024 W2-frag dwords
    int* col      = (int*)(wsW + 5120);                  // E
    float* dis    = (float*)(col + ((E + 15) & ~15));    // N
    ushort_t* h1  = (ushort_t*)(dis + ((N + 15) & ~15)); // 2*(N+1)*32 bf16
    unsigned* scratch = (unsigned*)(h1 + (((long long)(N + 1) * 64 + 31) & ~31LL));
    unsigned* pairs = scratch;            // nbk*cap dwords (~8.4MB), dead after bucket_build
    unsigned* z     = scratch;            // 2*(N+1)*16 dwords f16 halves (12.8MB)
    ushort_t* h2    = h1;                 // 2*(N+1)*16 bf16 halves (6.4MB), after h1 dead

    const int B = 256;
    const int PB = (E + EPB - 1) / EPB;
    const int NBR = (N + 15) >> 4;                      // 16-row units per half (6250)
    int bph = (NBR + 7) / 8;                            // blocks/half @ 4 waves x 2 iters
    int agg_blocks = ((2 * bph + 7) / 8) * 8;           // multiple of 8 for XCD mapping
    if (agg_blocks > 2048) agg_blocks = 2048;

    hipMemsetAsync(gcursor, 0, MAXB * sizeof(int), stream);
    k_partition<<<PB + 5, B, 0, stream>>>(esrc, edst, gcursor, pairs, E, nbk, cap, PB, W1, W2, wsW);
    k_bucket_build<<<nbk, B, 0, stream>>>(pairs, gcursor, rowptr, col, dis, (unsigned*)h1, cap, N);

    k_mm1<<<(N + 63) / 64, B, 0, stream>>>(x, wsW, dis, h1, N);

    // layer-1 aggregation: channel-halves, XCD-quad affinity, L2-resident-ish gathers
    k_gather1h<<<agg_blocks, B, 0, stream>>>((const unsigned*)h1, rowptr, col, dis, b1, z, N);

    // layer-2 transform (MFMA), writes h2 halves over dead h1
    k_mm2<<<(N + 63) / 64, B, 0, stream>>>(z, wsW + 4096, dis, h2, N);

    // final aggregation: channel-halves, fully L2-resident h2
    k_agg32h<<<agg_blocks, B, 0, stream>>>((const unsigned*)h2, rowptr, col, dis, b2, out, N);
}